// Round 1
// baseline (664.601 us; speedup 1.0000x reference)
//
#include <hip/hip_runtime.h>
#include <math.h>

#define BATCH 8
#define CH    64
#define NPTS  2048
#define KNN   20
#define OUTC  64

// Sorted (desc) insert into a 20-entry top-k list held in LDS.
__device__ __forceinline__ void insert20(float* nd, int* id, float v, int m) {
    int p = 19;
    while (p > 0 && nd[p-1] < v) { nd[p] = nd[p-1]; id[p] = id[p-1]; --p; }
    nd[p] = v; id[p] = m;
}

// Kernel A: y1t[b][m][o] = sum_c W[o][c] * x[b][c][m]
//           zt [b][n][o] = sum_c (W[o][64+c]-W[o][c]) * x[b][c][n] + bias[o]
//           xx [b][m]    = sum_c x[b][c][m]^2
__global__ __launch_bounds__(256) void edgeconv_prep(
    const float* __restrict__ x, const float* __restrict__ W,
    const float* __restrict__ bias,
    float* __restrict__ y1t, float* __restrict__ zt, float* __restrict__ xx)
{
    __shared__ __align__(16) float Wt1[64*64];   // [c][o]
    __shared__ __align__(16) float Wtd[64*64];   // [c][o]  (W2 - W1)
    __shared__ __align__(16) float xs [64*64];   // [c][m]
    const int tx  = threadIdx.x;
    const int bid = blockIdx.x;
    const int b   = bid >> 5;
    const int m0  = (bid & 31) << 6;
    const float* xb = x + (size_t)b * (CH * NPTS);

    {   // stage W transposed
        const int o  = tx >> 2;
        const int cb = (tx & 3) << 4;
        #pragma unroll
        for (int cc = 0; cc < 16; cc += 4) {
            const float4 w1 = *(const float4*)&W[o*128 + cb + cc];
            const float4 w2 = *(const float4*)&W[o*128 + 64 + cb + cc];
            const float a1[4] = {w1.x, w1.y, w1.z, w1.w};
            const float a2[4] = {w2.x, w2.y, w2.z, w2.w};
            #pragma unroll
            for (int e = 0; e < 4; ++e) {
                Wt1[(cb+cc+e)*64 + o] = a1[e];
                Wtd[(cb+cc+e)*64 + o] = a2[e] - a1[e];
            }
        }
    }
    #pragma unroll
    for (int it = 0; it < 4; ++it) {   // stage x tile [64c][64m]
        const int c = (tx >> 4) + (it << 4);
        const int j = (tx & 15) << 2;
        *(float4*)&xs[c*64 + j] = *(const float4*)&xb[(size_t)c*NPTS + m0 + j];
    }
    __syncthreads();

    if (tx < 64) {   // squared norms
        float s = 0.f;
        #pragma unroll
        for (int c = 0; c < 64; ++c) { const float v = xs[c*64 + tx]; s = fmaf(v, v, s); }
        xx[b*NPTS + m0 + tx] = s;
    }

    const int o  = tx & 63;   // lane = output channel (coalesced writes)
    const int mg = tx >> 6;   // wave -> 16-m chunk
    float y[16], z[16];
    const float bo = bias[o];
    #pragma unroll
    for (int i = 0; i < 16; ++i) { y[i] = 0.f; z[i] = bo; }
    #pragma unroll
    for (int c = 0; c < 64; ++c) {
        const float w1 = Wt1[c*64 + o];
        const float wd = Wtd[c*64 + o];
        float a[16];
        *(float4*)&a[0]  = *(const float4*)&xs[c*64 + mg*16 + 0];
        *(float4*)&a[4]  = *(const float4*)&xs[c*64 + mg*16 + 4];
        *(float4*)&a[8]  = *(const float4*)&xs[c*64 + mg*16 + 8];
        *(float4*)&a[12] = *(const float4*)&xs[c*64 + mg*16 + 12];
        #pragma unroll
        for (int i = 0; i < 16; ++i) {
            y[i] = fmaf(w1, a[i], y[i]);
            z[i] = fmaf(wd, a[i], z[i]);
        }
    }
    #pragma unroll
    for (int i = 0; i < 16; ++i) {
        const int m = m0 + mg*16 + i;
        y1t[((size_t)b*NPTS + m)*64 + o] = y[i];
        zt [((size_t)b*NPTS + m)*64 + o] = z[i];
    }
}

// Kernel K: fused kNN (distance Gram + streaming top-20) + gather + lrelu + max.
// One block = (batch b, 64-row tile). Rank key: 2*dot(n,m) - ||x_m||^2
// (per-row constant -||x_n||^2 dropped; rank-invariant).
__global__ __launch_bounds__(256) void edgeconv_main(
    const float* __restrict__ x,
    const float* __restrict__ y1t, const float* __restrict__ zt,
    const float* __restrict__ xx, float* __restrict__ out)
{
    __shared__ __align__(16) float xn [64*64];     // [c][i]
    __shared__ __align__(16) float xm [64*64];     // [c][j]
    __shared__ __align__(16) float S  [64*68];     // [i][j] pad 68 (272B = 17*16: b128-aligned, conflict-free scan)
    __shared__ __align__(16) float ndl[64*20];
    __shared__ __align__(16) int   idl[64*20];
    __shared__ __align__(16) float xxm[64];

    const int tx  = threadIdx.x;
    const int bid = blockIdx.x;
    const int b   = bid >> 5;
    const int n0  = (bid & 31) << 6;
    const float* xb = x + (size_t)b * (CH * NPTS);

    #pragma unroll
    for (int it = 0; it < 4; ++it) {
        const int c = (tx >> 4) + (it << 4);
        const int j = (tx & 15) << 2;
        *(float4*)&xn[c*64 + j] = *(const float4*)&xb[(size_t)c*NPTS + n0 + j];
        *(float4*)&xm[c*64 + j] = *(const float4*)&xb[(size_t)c*NPTS + j];
    }
    if (tx < 64) xxm[tx] = xx[b*NPTS + tx];
    for (int i = tx; i < 64*20; i += 256) { ndl[i] = -INFINITY; idl[i] = 0; }
    __syncthreads();

    const int ti = tx & 15;          // 4-row group
    const int tj = tx >> 4;          // 4-col group
    const int myrow = tx >> 2;       // scanner row (16 scanner lanes per wave)
    const bool scanner = ((tx & 3) == 0);
    float thr = -INFINITY;
    float* mynd = &ndl[myrow*20];
    int*   myid = &idl[myrow*20];

    for (int t = 0; t < 32; ++t) {
        float4 p0, p1, p2, p3;               // register prefetch of next m-tile
        float xxp = 0.f;
        const int tn = t + 1;
        const int j = (tx & 15) << 2;
        if (tn < 32) {
            const int mb = tn << 6;
            p0 = *(const float4*)&xb[(size_t)((tx>>4)+ 0)*NPTS + mb + j];
            p1 = *(const float4*)&xb[(size_t)((tx>>4)+16)*NPTS + mb + j];
            p2 = *(const float4*)&xb[(size_t)((tx>>4)+32)*NPTS + mb + j];
            p3 = *(const float4*)&xb[(size_t)((tx>>4)+48)*NPTS + mb + j];
            if (tx < 64) xxp = xx[b*NPTS + mb + tx];
        }

        float acc[4][4];
        #pragma unroll
        for (int i = 0; i < 4; ++i)
            #pragma unroll
            for (int jj = 0; jj < 4; ++jj) acc[i][jj] = 0.f;

        #pragma unroll
        for (int c = 0; c < 64; ++c) {
            float av[4], bv[4];
            *(float4*)&av[0] = *(const float4*)&xn[c*64 + ti*4];
            *(float4*)&bv[0] = *(const float4*)&xm[c*64 + tj*4];
            #pragma unroll
            for (int i = 0; i < 4; ++i)
                #pragma unroll
                for (int jj = 0; jj < 4; ++jj)
                    acc[i][jj] = fmaf(av[i], bv[jj], acc[i][jj]);
        }

        float xq[4];
        *(float4*)&xq[0] = *(const float4*)&xxm[tj*4];
        #pragma unroll
        for (int r = 0; r < 4; ++r) {
            float sv[4];
            #pragma unroll
            for (int e = 0; e < 4; ++e) sv[e] = fmaf(2.f, acc[r][e], -xq[e]);
            *(float4*)&S[(ti*4 + r)*68 + tj*4] = *(float4*)&sv[0];
        }
        __syncthreads();

        if (scanner) {   // streaming top-20: strict > keeps lowest index on ties (matches lax.top_k)
            const int mb = t << 6;
            for (int jj = 0; jj < 16; ++jj) {
                float v[4];
                *(float4*)&v[0] = *(const float4*)&S[myrow*68 + jj*4];
                #pragma unroll
                for (int e = 0; e < 4; ++e) {
                    if (v[e] > thr) { insert20(mynd, myid, v[e], mb + jj*4 + e); thr = mynd[19]; }
                }
            }
        }
        __syncthreads();

        if (tn < 32) {   // commit prefetched tile
            *(float4*)&xm[((tx>>4)+ 0)*64 + j] = p0;
            *(float4*)&xm[((tx>>4)+16)*64 + j] = p1;
            *(float4*)&xm[((tx>>4)+32)*64 + j] = p2;
            *(float4*)&xm[((tx>>4)+48)*64 + j] = p3;
            if (tx < 64) xxm[tx] = xxp;
        }
        __syncthreads();
    }

    // Output: out[b,o,n] = max_k lrelu(y1t[m_k][o] + zt[n][o]); lane = o, wave handles 16 rows.
    const int lane = tx & 63;
    const int w    = tx >> 6;
    const float* y1b = y1t + (size_t)b * NPTS * 64;
    const float* ztb = zt  + (size_t)b * NPTS * 64;
    float* outbuf = S;   // reuse (stride 68)

    for (int rr = 0; rr < 16; ++rr) {
        const int r = w*16 + rr;
        const int n = n0 + r;
        int ml[20];
        *(int4*)&ml[0]  = *(const int4*)&idl[r*20 + 0];
        *(int4*)&ml[4]  = *(const int4*)&idl[r*20 + 4];
        *(int4*)&ml[8]  = *(const int4*)&idl[r*20 + 8];
        *(int4*)&ml[12] = *(const int4*)&idl[r*20 + 12];
        *(int4*)&ml[16] = *(const int4*)&idl[r*20 + 16];
        const float zv = ztb[(size_t)n*64 + lane];
        float acc = -INFINITY;
        #pragma unroll
        for (int k = 0; k < 20; ++k) {
            const float v = y1b[(size_t)ml[k]*64 + lane];
            float h = v + zv;
            h = fmaxf(h, 0.2f*h);          // leaky relu, exact
            acc = fmaxf(acc, h);
        }
        outbuf[r*68 + lane] = acc;
    }
    __syncthreads();
    float* ob = out + (size_t)b * OUTC * NPTS;
    #pragma unroll
    for (int q = 0; q < 16; ++q) {
        const int o = w*16 + q;
        ob[(size_t)o*NPTS + n0 + lane] = outbuf[lane*68 + o];   // coalesced 256B rows
    }
}

extern "C" void kernel_launch(void* const* d_in, const int* in_sizes, int n_in,
                              void* d_out, int out_size, void* d_ws, size_t ws_size,
                              hipStream_t stream) {
    const float* x    = (const float*)d_in[0];   // (8,64,2048)
    const float* W    = (const float*)d_in[1];   // (64,128)
    const float* bias = (const float*)d_in[2];   // (64,)
    float* out = (float*)d_out;                  // (8,64,2048)

    // workspace: y1t (4MB) | zt (4MB) | xx (64KB)  => 8.45MB
    float* y1t = (float*)d_ws;
    float* zt  = y1t + (size_t)BATCH * NPTS * 64;
    float* xx  = zt  + (size_t)BATCH * NPTS * 64;

    edgeconv_prep<<<BATCH * (NPTS/64), 256, 0, stream>>>(x, W, bias, y1t, zt, xx);
    edgeconv_main<<<BATCH * (NPTS/64), 256, 0, stream>>>(x, y1t, zt, xx, out);
}

// Round 3
// 261.790 us; speedup vs baseline: 2.5387x; 2.5387x over previous
//
#include <hip/hip_runtime.h>
#include <math.h>

#define BATCH 8
#define CH    64
#define NPTS  2048
#define KNN   20
#define OUTC  64

// Kernel A: y1t[b][m][o] = sum_c W[o][c] * x[b][c][m]
//           zt [b][n][o] = sum_c (W[o][64+c]-W[o][c]) * x[b][c][n] + bias[o]
//           xx [b][m]    = sum_c x[b][c][m]^2
__global__ __launch_bounds__(256) void edgeconv_prep(
    const float* __restrict__ x, const float* __restrict__ W,
    const float* __restrict__ bias,
    float* __restrict__ y1t, float* __restrict__ zt, float* __restrict__ xx)
{
    __shared__ __align__(16) float Wt1[64*64];   // [c][o]
    __shared__ __align__(16) float Wtd[64*64];   // [c][o]  (W2 - W1)
    __shared__ __align__(16) float xs [64*64];   // [c][m]
    const int tx  = threadIdx.x;
    const int bid = blockIdx.x;
    const int b   = bid >> 5;
    const int m0  = (bid & 31) << 6;
    const float* xb = x + (size_t)b * (CH * NPTS);

    {   // stage W transposed
        const int o  = tx >> 2;
        const int cb = (tx & 3) << 4;
        #pragma unroll
        for (int cc = 0; cc < 16; cc += 4) {
            const float4 w1 = *(const float4*)&W[o*128 + cb + cc];
            const float4 w2 = *(const float4*)&W[o*128 + 64 + cb + cc];
            const float a1[4] = {w1.x, w1.y, w1.z, w1.w};
            const float a2[4] = {w2.x, w2.y, w2.z, w2.w};
            #pragma unroll
            for (int e = 0; e < 4; ++e) {
                Wt1[(cb+cc+e)*64 + o] = a1[e];
                Wtd[(cb+cc+e)*64 + o] = a2[e] - a1[e];
            }
        }
    }
    #pragma unroll
    for (int it = 0; it < 4; ++it) {   // stage x tile [64c][64m]
        const int c = (tx >> 4) + (it << 4);
        const int j = (tx & 15) << 2;
        *(float4*)&xs[c*64 + j] = *(const float4*)&xb[(size_t)c*NPTS + m0 + j];
    }
    __syncthreads();

    if (tx < 64) {   // squared norms
        float s = 0.f;
        #pragma unroll
        for (int c = 0; c < 64; ++c) { const float v = xs[c*64 + tx]; s = fmaf(v, v, s); }
        xx[b*NPTS + m0 + tx] = s;
    }

    const int o  = tx & 63;   // lane = output channel (coalesced writes)
    const int mg = tx >> 6;   // wave -> 16-m chunk
    float y[16], z[16];
    const float bo = bias[o];
    #pragma unroll
    for (int i = 0; i < 16; ++i) { y[i] = 0.f; z[i] = bo; }
    #pragma unroll
    for (int c = 0; c < 64; ++c) {
        const float w1 = Wt1[c*64 + o];
        const float wd = Wtd[c*64 + o];
        float a[16];
        *(float4*)&a[0]  = *(const float4*)&xs[c*64 + mg*16 + 0];
        *(float4*)&a[4]  = *(const float4*)&xs[c*64 + mg*16 + 4];
        *(float4*)&a[8]  = *(const float4*)&xs[c*64 + mg*16 + 8];
        *(float4*)&a[12] = *(const float4*)&xs[c*64 + mg*16 + 12];
        #pragma unroll
        for (int i = 0; i < 16; ++i) {
            y[i] = fmaf(w1, a[i], y[i]);
            z[i] = fmaf(wd, a[i], z[i]);
        }
    }
    #pragma unroll
    for (int i = 0; i < 16; ++i) {
        const int m = m0 + mg*16 + i;
        y1t[((size_t)b*NPTS + m)*64 + o] = y[i];
        zt [((size_t)b*NPTS + m)*64 + o] = z[i];
    }
}

// Main kernel: fused kNN + gather + lrelu + max.
// One block = (batch b, 64-row tile). Rank key: 2*dot(n,m) - ||x_m||^2.
// Top-20 per lane kept in REGISTERS (ascending d[0..19], d[0]=threshold);
// candidates buffered per tile as 4-bit codes in a u64, drained via __any loop.
__global__ __launch_bounds__(256) void edgeconv_main(
    const float* __restrict__ x,
    const float* __restrict__ y1t, const float* __restrict__ zt,
    const float* __restrict__ xx, float* __restrict__ out)
{
    __shared__ __align__(16) char pool[50432];
    float* xn  = (float*)pool;              // [64c][64n] 16384
    float* xm  = (float*)(pool + 16384);    // [64c][64m] 16384
    float* S   = (float*)(pool + 32768);    // [64n][68]  17408 (pad 68)
    float* xxm = (float*)(pool + 50176);    // [64]       256
    // phase-2 aliases (all underlying data dead when first touched):
    float* mv     = (float*)pool;           // [64][80] merge values (over xn/xm)
    int*   mi     = (int*)(pool + 20480);   // [64][80] merge indices (over xm/S-low)
    int*   ml     = (int*)(pool + 40960);   // [64][20] final knn idx (S-high)
    float* outbuf = (float*)pool;           // [64][68] epilogue staging (over mv)

    const int tx  = threadIdx.x;
    const int bid = blockIdx.x;
    const int b   = bid >> 5;
    const int n0  = (bid & 31) << 6;
    const float* xb = x + (size_t)b * (CH * NPTS);

    #pragma unroll
    for (int it = 0; it < 4; ++it) {
        const int c = (tx >> 4) + (it << 4);
        const int j = (tx & 15) << 2;
        *(float4*)&xn[c*64 + j] = *(const float4*)&xb[(size_t)c*NPTS + n0 + j];
        *(float4*)&xm[c*64 + j] = *(const float4*)&xb[(size_t)c*NPTS + j];
    }
    if (tx < 64) xxm[tx] = xx[b*NPTS + tx];
    __syncthreads();

    const int ti = tx & 15;          // Gram: 4-row group
    const int tj = tx >> 4;          // Gram: 4-col group
    const int r  = tx >> 2;          // scan: my row
    const int qd = tx & 3;           // scan: my col-quarter (16 cols)

    // register top-20 (ascending; d[0] = current 20th = threshold)
    float d[KNN]; int id[KNN];
    #pragma unroll
    for (int k = 0; k < KNN; ++k) { d[k] = -INFINITY; id[k] = 0; }
    float thr = -INFINITY;

    for (int t = 0; t < 32; ++t) {
        float4 p0, p1, p2, p3;               // register prefetch of next m-tile
        float xxp = 0.f;
        const int tn = t + 1;
        const int j = (tx & 15) << 2;
        if (tn < 32) {
            const int mb = tn << 6;
            p0 = *(const float4*)&xb[(size_t)((tx>>4)+ 0)*NPTS + mb + j];
            p1 = *(const float4*)&xb[(size_t)((tx>>4)+16)*NPTS + mb + j];
            p2 = *(const float4*)&xb[(size_t)((tx>>4)+32)*NPTS + mb + j];
            p3 = *(const float4*)&xb[(size_t)((tx>>4)+48)*NPTS + mb + j];
            if (tx < 64) xxp = xx[b*NPTS + mb + tx];
        }

        float acc[4][4];
        #pragma unroll
        for (int i = 0; i < 4; ++i)
            #pragma unroll
            for (int jj = 0; jj < 4; ++jj) acc[i][jj] = 0.f;

        #pragma unroll
        for (int c = 0; c < 64; ++c) {
            float av[4], bv[4];
            *(float4*)&av[0] = *(const float4*)&xn[c*64 + ti*4];
            *(float4*)&bv[0] = *(const float4*)&xm[c*64 + tj*4];
            #pragma unroll
            for (int i = 0; i < 4; ++i)
                #pragma unroll
                for (int jj = 0; jj < 4; ++jj)
                    acc[i][jj] = fmaf(av[i], bv[jj], acc[i][jj]);
        }

        float xq[4];
        *(float4*)&xq[0] = *(const float4*)&xxm[tj*4];
        #pragma unroll
        for (int rr = 0; rr < 4; ++rr) {
            float sv[4];
            #pragma unroll
            for (int e = 0; e < 4; ++e) sv[e] = fmaf(2.f, acc[rr][e], -xq[e]);
            *(float4*)&S[(ti*4 + rr)*68 + tj*4] = *(float4*)&sv[0];
        }
        __syncthreads();   // S ready; all Gram reads of xm done

        if (tn < 32) {     // commit prefetched tile (no one reads xm this phase)
            *(float4*)&xm[((tx>>4)+ 0)*64 + j] = p0;
            *(float4*)&xm[((tx>>4)+16)*64 + j] = p1;
            *(float4*)&xm[((tx>>4)+32)*64 + j] = p2;
            *(float4*)&xm[((tx>>4)+48)*64 + j] = p3;
            if (tx < 64) xxm[tx] = xxp;
        }

        // ---- scan: guard 16 values, queue passing column-codes in a u64 ----
        float v[16];
        *(float4*)&v[0]  = *(const float4*)&S[r*68 + qd*16 + 0];
        *(float4*)&v[4]  = *(const float4*)&S[r*68 + qd*16 + 4];
        *(float4*)&v[8]  = *(const float4*)&S[r*68 + qd*16 + 8];
        *(float4*)&v[12] = *(const float4*)&S[r*68 + qd*16 + 12];

        unsigned long long enc = 0ULL;
        int cnt = 0;
        #pragma unroll
        for (int e = 0; e < 16; ++e) {
            if (v[e] > thr) { enc |= ((unsigned long long)e) << (4*cnt); ++cnt; }
        }

        // ---- drain queue: wave pays max(cnt) ladders, not 64 ----
        const float* Srow = &S[r*68 + qd*16];
        const int base = (t << 6) + qd*16;
        int qq = 0;
        int   e0 = (int)(enc & 15ULL);
        float v0 = Srow[e0];
        while (__any(qq < cnt)) {
            const int sh = (4*(qq+1)) & 63;
            const int e1 = (int)((enc >> sh) & 15ULL);
            const float v1 = Srow[e1];              // prefetch next candidate
            if (qq < cnt && v0 > thr) {
                const float iv = v0; const int ii = base + e0;
                bool ci = true;                     // iv > d[0] guaranteed
                #pragma unroll
                for (int s = 0; s < KNN; ++s) {
                    const bool  cn = (s < KNN-1) ? (iv > d[s+1]) : false;
                    const float dn = (s < KNN-1) ? d[s+1] : 0.f;
                    const int   gn = (s < KNN-1) ? id[s+1] : 0;
                    const float ndv = cn ? dn : (ci ? iv : d[s]);
                    const int   nid = cn ? gn : (ci ? ii : id[s]);
                    d[s] = ndv; id[s] = nid;
                    ci = cn;
                }
                thr = d[0];
            }
            v0 = v1; e0 = e1; ++qq;
        }
        __syncthreads();   // scan done (S free), xm committed
    }

    // ---- dump per-lane sorted lists, 4-way merge per row ----
    #pragma unroll
    for (int k = 0; k < KNN; ++k) {
        mv[r*80 + qd*20 + k] = d[k];
        mi[r*80 + qd*20 + k] = id[k];
    }
    __syncthreads();

    if (qd == 0) {   // one merge lane per row; comparator = (v desc, idx asc) = lax.top_k order
        const int rb = r*80;
        int a0 = 19, a1 = 19, a2 = 19, a3 = 19;
        float h0 = mv[rb+19], h1 = mv[rb+39], h2 = mv[rb+59], h3 = mv[rb+79];
        int   g0 = mi[rb+19], g1 = mi[rb+39], g2 = mi[rb+59], g3 = mi[rb+79];
        for (int k = 0; k < KNN; ++k) {
            float bvv = h0; int bg = g0; int bj = 0;
            if (h1 > bvv || (h1 == bvv && g1 < bg)) { bvv = h1; bg = g1; bj = 1; }
            if (h2 > bvv || (h2 == bvv && g2 < bg)) { bvv = h2; bg = g2; bj = 2; }
            if (h3 > bvv || (h3 == bvv && g3 < bg)) { bvv = h3; bg = g3; bj = 3; }
            ml[r*20 + k] = bg;
            if      (bj == 0) { --a0; const bool ok = a0 >= 0; h0 = ok ? mv[rb+a0]    : -INFINITY; g0 = ok ? mi[rb+a0]    : 0; }
            else if (bj == 1) { --a1; const bool ok = a1 >= 0; h1 = ok ? mv[rb+20+a1] : -INFINITY; g1 = ok ? mi[rb+20+a1] : 0; }
            else if (bj == 2) { --a2; const bool ok = a2 >= 0; h2 = ok ? mv[rb+40+a2] : -INFINITY; g2 = ok ? mi[rb+40+a2] : 0; }
            else              { --a3; const bool ok = a3 >= 0; h3 = ok ? mv[rb+60+a3] : -INFINITY; g3 = ok ? mi[rb+60+a3] : 0; }
        }
    }
    __syncthreads();

    // ---- epilogue: out[b,o,n] = max_k lrelu(y1t[m_k][o] + zt[n][o]) ----
    const int lane = tx & 63;
    const int w    = tx >> 6;
    const float* y1b = y1t + (size_t)b * NPTS * 64;
    const float* ztb = zt  + (size_t)b * NPTS * 64;

    for (int rr = 0; rr < 16; ++rr) {
        const int rw = w*16 + rr;
        const int n  = n0 + rw;
        int mlr[20];
        *(int4*)&mlr[0]  = *(const int4*)&ml[rw*20 + 0];
        *(int4*)&mlr[4]  = *(const int4*)&ml[rw*20 + 4];
        *(int4*)&mlr[8]  = *(const int4*)&ml[rw*20 + 8];
        *(int4*)&mlr[12] = *(const int4*)&ml[rw*20 + 12];
        *(int4*)&mlr[16] = *(const int4*)&ml[rw*20 + 16];
        const float zv = ztb[(size_t)n*64 + lane];
        float acc = -INFINITY;
        #pragma unroll
        for (int k = 0; k < KNN; ++k) {
            const float vv = y1b[(size_t)mlr[k]*64 + lane];
            float h = vv + zv;
            h = fmaxf(h, 0.2f*h);          // leaky relu, exact
            acc = fmaxf(acc, h);
        }
        outbuf[rw*68 + lane] = acc;
    }
    __syncthreads();
    float* ob = out + (size_t)b * OUTC * NPTS;
    #pragma unroll
    for (int qo = 0; qo < 16; ++qo) {
        const int o = w*16 + qo;
        ob[(size_t)o*NPTS + n0 + lane] = outbuf[lane*68 + o];   // coalesced 256B rows
    }
}

extern "C" void kernel_launch(void* const* d_in, const int* in_sizes, int n_in,
                              void* d_out, int out_size, void* d_ws, size_t ws_size,
                              hipStream_t stream) {
    const float* x    = (const float*)d_in[0];   // (8,64,2048)
    const float* W    = (const float*)d_in[1];   // (64,128)
    const float* bias = (const float*)d_in[2];   // (64,)
    float* out = (float*)d_out;                  // (8,64,2048)

    // workspace: y1t (4MB) | zt (4MB) | xx (64KB)
    float* y1t = (float*)d_ws;
    float* zt  = y1t + (size_t)BATCH * NPTS * 64;
    float* xx  = zt  + (size_t)BATCH * NPTS * 64;

    edgeconv_prep<<<BATCH * (NPTS/64), 256, 0, stream>>>(x, W, bias, y1t, zt, xx);
    edgeconv_main<<<BATCH * (NPTS/64), 256, 0, stream>>>(x, y1t, zt, xx, out);
}